// Round 2
// baseline (647.180 us; speedup 1.0000x reference)
//
#include <hip/hip_runtime.h>

#define N_    32
#define CIN_  64
#define COUT_ 64
#define T_    1024
#define V_    25
#define K_    3
#define TT_   2        // t-values per gcn_main block
#define EPSV  1e-5f

// ws float offsets
#define WS_BIAS2  2112     // [64 c][25 w]
#define WS_SUM    9856     // [8 slot][64 c]
#define WS_SQ     10368
#define WS_SCALE  10880
#define WS_SHIFT  10944
#define WS_A2F    11008    // A2 B-frags: 5 nt * 64 lane * 8 bf16
#define WS_W2F    12288    // W2 B-frags: 24 g * 64 lane * 8 bf16

typedef __attribute__((ext_vector_type(4))) float f32x4;
typedef __attribute__((ext_vector_type(8))) short short8;   // 8 bf16 = 4 VGPRs

__device__ __forceinline__ unsigned short f_to_bf16u(float f) {
    unsigned int b = __float_as_uint(f);
    b += 0x7fffu + ((b >> 16) & 1u);   // RNE
    return (unsigned short)(b >> 16);
}

// ---- kernel 0: bias2, stat-zero, MFMA B-operand fragment tables ------------
__global__ void gcn_prep(const float* __restrict__ A, const float* __restrict__ PA,
                         const float* __restrict__ b, const float* __restrict__ W,
                         float* ws) {
    __shared__ float cs[K_ * V_];
    const int tid = threadIdx.x;
    const int blk = blockIdx.x;

    if (blk == 0) {
        if (tid < K_ * V_) {
            int k = tid / V_, w = tid % V_;
            float s = 0.f;
            for (int v = 0; v < V_; ++v) {
                int idx = (k * V_ + v) * V_ + w;
                s += A[idx] + PA[idx];
            }
            cs[tid] = s;
        }
        for (int f = tid; f < 1024; f += 256) ws[WS_SUM + f] = 0.f;
        __syncthreads();
        for (int f = tid; f < COUT_ * V_; f += 256) {
            int c = f / V_, w = f - (f / V_) * V_;
            float s = 0.f;
            for (int k = 0; k < K_; ++k) s += b[k * COUT_ + c] * cs[k * V_ + w];
            ws[WS_BIAS2 + f] = s;
        }
    } else if (blk == 1) {
        // A2 frags (GEMM1 B-operand): col=(k,w)=nt*16+(l&15), kdim v=(l>>4)*8+j
        unsigned short* a2 = (unsigned short*)(ws + WS_A2F);
        for (int f = tid; f < 5 * 64 * 8; f += 256) {
            int j  = f & 7;
            int l  = (f >> 3) & 63;
            int nt = f >> 9;
            int col = nt * 16 + (l & 15);
            int v   = (l >> 4) * 8 + j;
            float val = 0.f;
            if (col < 75 && v < V_) {
                int k = col / 25, w = col - (col / 25) * 25;
                int idx = (k * V_ + v) * V_ + w;
                val = A[idx] + PA[idx];
            }
            a2[f] = f_to_bf16u(val);
        }
    } else {
        // W2 frags (GEMM2 B-operand): col c=(g/6)*16+(l&15), kci=(g%6)*32+(l>>4)*8+j
        unsigned short* w2 = (unsigned short*)(ws + WS_W2F);
        int lo = (blk - 2) * 6144;
        for (int f = lo + tid; f < lo + 6144; f += 256) {
            int j = f & 7;
            int l = (f >> 3) & 63;
            int g = f >> 9;
            int kci = (g % 6) * 32 + (l >> 4) * 8 + j;
            int c   = (g / 6) * 16 + (l & 15);
            int k = kci >> 6, ci = kci & 63;
            w2[f] = f_to_bf16u(W[(k * 64 + c) * 64 + ci]);
        }
    }
}

// ---- kernel 1: fused conv+agg via two MFMA stages, TT=2 ---------------------
// block = 256 (4 waves); grid = 32 n x 512 t-chunks = 16384
// LDS: X  [128 rows = t*64+ci][40 v-pad] bf16 = 10240 B
//      xA [64 rows = t*25+w (50 real)][200 kci-pad] bf16 = 25600 B  (total 35840)
__global__ __launch_bounds__(256, 4)
void gcn_main(const float* __restrict__ x, float* __restrict__ ws,
              float* __restrict__ out) {
    __shared__ __align__(16) unsigned char smem[35840];
    unsigned short* xs16 = (unsigned short*)smem;
    unsigned short* xa16 = (unsigned short*)(smem + 10240);

    const int tid = threadIdx.x;
    const int bid = blockIdx.x;
    const int n   = bid >> 9;
    const int tc  = bid & 511;
    const int l   = tid & 63;
    const int wv  = tid >> 6;
    const int llo = l & 15;
    const int lhi = l >> 4;

    // zero X region (v-pad 25..39 must be 0 for the K=32 MFMA)
    {
        unsigned int* xu = (unsigned int*)xs16;
        #pragma unroll
        for (int i = 0; i < 10; ++i) xu[i * 256 + tid] = 0u;
    }
    __syncthreads();

    // ---- stage x -> bf16 LDS (float2 global reads; TT=2 chunk is 8B-aligned)
    const float2* xg = (const float2*)x;
    for (int f = tid; f < CIN_ * 25; f += 256) {
        int ci = f / 25;
        int j  = f - ci * 25;
        float2 g = xg[(size_t)(n * CIN_ + ci) * 12800 + tc * 25 + j];
        int flat = 2 * j;                      // 0..48
        int t = (flat >= 25) ? 1 : 0;
        int v = flat - 25 * t;
        xs16[(t * 64 + ci) * 40 + v] = f_to_bf16u(g.x);
        int v2 = v + 1, t2 = t;
        if (v2 == 25) { v2 = 0; t2 = 1; }
        xs16[(t2 * 64 + ci) * 40 + v2] = f_to_bf16u(g.y);
    }
    __syncthreads();

    // ---- GEMM1: xA[(t,w)][(k,ci)] = X[(t,ci)][v] x Af[v][(k,w)] ----
    // t-major rows => C quad (i=0..3) = 4 consecutive ci => one b64 LDS write
    {
        const unsigned short* a2g = (const unsigned short*)(ws + WS_A2F);
        short8 a2f[5];
        #pragma unroll
        for (int nt = 0; nt < 5; ++nt)
            a2f[nt] = *(const short8*)(a2g + (nt * 64 + l) * 8);

        #pragma unroll
        for (int q = 0; q < 2; ++q) {
            int mt = wv * 2 + q;
            short8 xf = *(const short8*)(xs16 + (mt * 16 + llo) * 40 + lhi * 8);
            int rb = mt * 16 + lhi * 4;
            int t  = rb >> 6;
            int ci = rb & 63;
            #pragma unroll
            for (int nt = 0; nt < 5; ++nt) {
                f32x4 z = {0.f, 0.f, 0.f, 0.f};
                f32x4 acc = __builtin_amdgcn_mfma_f32_16x16x32_bf16(xf, a2f[nt], z, 0, 0, 0);
                int col = nt * 16 + llo;
                if (col < 75) {
                    int k = (col >= 50) ? 2 : ((col >= 25) ? 1 : 0);
                    int w = col - k * 25;
                    unsigned int lo = (unsigned int)f_to_bf16u(acc[0]) |
                                      ((unsigned int)f_to_bf16u(acc[1]) << 16);
                    unsigned int hi = (unsigned int)f_to_bf16u(acc[2]) |
                                      ((unsigned int)f_to_bf16u(acc[3]) << 16);
                    uint2 pk; pk.x = lo; pk.y = hi;
                    *(uint2*)(xa16 + (t * 25 + w) * 200 + k * 64 + ci) = pk;
                }
            }
        }
    }
    __syncthreads();

    // ---- GEMM2 + fused epilogue: direct global store + shuffle stats ----
    {
        const unsigned short* w2g = (const unsigned short*)(ws + WS_W2F);
        short8 w2f[6];
        #pragma unroll
        for (int kk = 0; kk < 6; ++kk)
            w2f[kk] = *(const short8*)(w2g + ((wv * 6 + kk) * 64 + l) * 8);

        const int c = wv * 16 + llo;
        const size_t obase = ((size_t)(n * COUT_ + c)) * 25600 + (size_t)tc * 50;
        float lsum = 0.f, lsq = 0.f;

        #pragma unroll
        for (int mt = 0; mt < 4; ++mt) {
            f32x4 acc = {0.f, 0.f, 0.f, 0.f};
            #pragma unroll
            for (int kk = 0; kk < 6; ++kk) {
                short8 a = *(const short8*)(xa16 + (mt * 16 + llo) * 200 + kk * 32 + lhi * 8);
                acc = __builtin_amdgcn_mfma_f32_16x16x32_bf16(a, w2f[kk], acc, 0, 0, 0);
            }
            int rbase = mt * 16 + lhi * 4;
            #pragma unroll
            for (int i = 0; i < 4; ++i) {
                int r = rbase + i;                     // r = t2*25 + w2, valid < 50
                if (r < 50) {
                    int t2 = (r >= 25) ? 1 : 0;
                    int w2 = r - 25 * t2;
                    float v = acc[i] + ws[WS_BIAS2 + c * 25 + w2];
                    out[obase + r] = v;
                    lsum += v;
                    lsq = fmaf(v, v, lsq);
                }
            }
        }
        // reduce stats across lhi groups (lanes ^16, ^32) -> one atomic per c
        lsum += __shfl_xor(lsum, 16);
        lsum += __shfl_xor(lsum, 32);
        lsq  += __shfl_xor(lsq, 16);
        lsq  += __shfl_xor(lsq, 32);
        if (l < 16) {
            int slot = bid & 7;
            atomicAdd(&ws[WS_SUM + slot * 64 + c], lsum);
            atomicAdd(&ws[WS_SQ  + slot * 64 + c], lsq);
        }
    }
}

// ---- kernel 2: finalize BN stats -------------------------------------------
__global__ void gcn_stats(float* ws, const float* __restrict__ gamma,
                          const float* __restrict__ beta) {
    int c = threadIdx.x;
    if (c < COUT_) {
        float s = 0.f, q = 0.f;
        #pragma unroll
        for (int slot = 0; slot < 8; ++slot) {
            s += ws[WS_SUM + slot * 64 + c];
            q += ws[WS_SQ  + slot * 64 + c];
        }
        const float cnt = (float)(N_ * T_ * V_);   // 819200
        float mu  = s / cnt;
        float var = q / cnt - mu * mu;
        float rs  = rsqrtf(var + EPSV);
        float sc  = gamma[c] * rs;
        ws[WS_SCALE + c] = sc;
        ws[WS_SHIFT + c] = fmaf(-mu, sc, beta[c]);
    }
}

// ---- kernel 3: BN apply + residual + ReLU, in-place on d_out ---------------
__global__ __launch_bounds__(256)
void gcn_finish(const float* __restrict__ x, const float* __restrict__ ws,
                float* __restrict__ out) {
    int bid = blockIdx.x;            // n*64 + c
    int c = bid & 63;
    float sc = ws[WS_SCALE + c];
    float sh = ws[WS_SHIFT + c];
    size_t base4 = (size_t)bid * 6400;
    const float4* x4 = (const float4*)x;
    float4* o4 = (float4*)out;
    #pragma unroll 2
    for (int it = 0; it < 25; ++it) {
        size_t i = base4 + it * 256 + threadIdx.x;
        float4 a  = o4[i];
        float4 xv = x4[i];
        a.x = fmaxf(0.f, fmaf(a.x, sc, sh) + xv.x);
        a.y = fmaxf(0.f, fmaf(a.y, sc, sh) + xv.y);
        a.z = fmaxf(0.f, fmaf(a.z, sc, sh) + xv.z);
        a.w = fmaxf(0.f, fmaf(a.w, sc, sh) + xv.w);
        o4[i] = a;
    }
}

extern "C" void kernel_launch(void* const* d_in, const int* in_sizes, int n_in,
                              void* d_out, int out_size, void* d_ws, size_t ws_size,
                              hipStream_t stream) {
    (void)in_sizes; (void)n_in; (void)out_size; (void)ws_size;
    const float* x     = (const float*)d_in[0];
    const float* W     = (const float*)d_in[1];
    const float* b     = (const float*)d_in[2];
    const float* A     = (const float*)d_in[3];
    const float* PA    = (const float*)d_in[4];
    const float* gamma = (const float*)d_in[5];
    const float* beta  = (const float*)d_in[6];
    float* out = (float*)d_out;
    float* ws  = (float*)d_ws;

    gcn_prep<<<4, 256, 0, stream>>>(A, PA, b, W, ws);
    gcn_main<<<N_ * (T_ / TT_), 256, 0, stream>>>(x, ws, out);
    gcn_stats<<<1, 64, 0, stream>>>(ws, gamma, beta);
    gcn_finish<<<N_ * COUT_, 256, 0, stream>>>(x, ws, out);
}

// Round 4
// 556.996 us; speedup vs baseline: 1.1619x; 1.1619x over previous
//
#include <hip/hip_runtime.h>

#define N_    32
#define CIN_  64
#define COUT_ 64
#define T_    1024
#define V_    25
#define K_    3
#define EPSV  1e-5f

#define CHUNKS_TOTAL   16384      // 32 n * 512 tc  (2 t-values per chunk)
#define GRID_MAIN      1024
#define ITERS          (CHUNKS_TOTAL / GRID_MAIN)   // 16

// ws float offsets
#define WS_BIAS2  2112     // [64 c][25 w]
#define WS_SUM    9856     // [8 slot][64 c]
#define WS_SQ     10368
#define WS_SCALE  10880
#define WS_SHIFT  10944
#define WS_A2F    11008    // A2 B-frags: 5 nt * 64 lane * 8 bf16
#define WS_W2F    12288    // W2 frags: 24 g * 64 lane * 8 bf16

typedef __attribute__((ext_vector_type(4))) float f32x4;
// 4-byte-aligned vector load type: x rows start at odd multiples of 25 floats,
// so 16B alignment is NOT guaranteed — align(4) keeps the dwordx4 load legal.
typedef __attribute__((ext_vector_type(4), aligned(4))) float f32x4u;
typedef __attribute__((ext_vector_type(8))) short short8;   // 8 bf16 = 4 VGPRs

__device__ __forceinline__ unsigned short f_to_bf16u(float f) {
    unsigned int b = __float_as_uint(f);
    b += 0x7fffu + ((b >> 16) & 1u);   // RNE
    return (unsigned short)(b >> 16);
}

__device__ __forceinline__ short8 pack8(const f32x4& a, const f32x4& b) {
    short8 r;
    r[0] = (short)f_to_bf16u(a[0]); r[1] = (short)f_to_bf16u(a[1]);
    r[2] = (short)f_to_bf16u(a[2]); r[3] = (short)f_to_bf16u(a[3]);
    r[4] = (short)f_to_bf16u(b[0]); r[5] = (short)f_to_bf16u(b[1]);
    r[6] = (short)f_to_bf16u(b[2]); r[7] = (short)f_to_bf16u(b[3]);
    return r;
}

// ---- kernel 0: bias2, stat-zero, MFMA B-operand fragment tables ------------
__global__ void gcn_prep(const float* __restrict__ A, const float* __restrict__ PA,
                         const float* __restrict__ b, const float* __restrict__ W,
                         float* ws) {
    __shared__ float cs[K_ * V_];
    const int tid = threadIdx.x;
    const int blk = blockIdx.x;

    if (blk == 0) {
        if (tid < K_ * V_) {
            int k = tid / V_, w = tid % V_;
            float s = 0.f;
            for (int v = 0; v < V_; ++v) {
                int idx = (k * V_ + v) * V_ + w;
                s += A[idx] + PA[idx];
            }
            cs[tid] = s;
        }
        for (int f = tid; f < 1024; f += 256) ws[WS_SUM + f] = 0.f;
        __syncthreads();
        for (int f = tid; f < COUT_ * V_; f += 256) {
            int c = f / V_, w = f - (f / V_) * V_;
            float s = 0.f;
            for (int k = 0; k < K_; ++k) s += b[k * COUT_ + c] * cs[k * V_ + w];
            ws[WS_BIAS2 + f] = s;
        }
    } else if (blk == 1) {
        // A2 frags (GEMM1 B-operand): col=(k,w)=nt*16+(l&15), kdim v=(l>>4)*8+j
        unsigned short* a2 = (unsigned short*)(ws + WS_A2F);
        for (int f = tid; f < 5 * 64 * 8; f += 256) {
            int j  = f & 7;
            int l  = (f >> 3) & 63;
            int nt = f >> 9;
            int col = nt * 16 + (l & 15);
            int v   = (l >> 4) * 8 + j;
            float val = 0.f;
            if (col < 75 && v < V_) {
                int k = col / 25, w = col - (col / 25) * 25;
                int idx = (k * V_ + v) * V_ + w;
                val = A[idx] + PA[idx];
            }
            a2[f] = f_to_bf16u(val);
        }
    } else {
        // W2 frags: row/col c=(g/6)*16+(l&15), kci=(g%6)*32+(l>>4)*8+j
        unsigned short* w2 = (unsigned short*)(ws + WS_W2F);
        int lo = (blk - 2) * 6144;
        for (int f = lo + tid; f < lo + 6144; f += 256) {
            int j = f & 7;
            int l = (f >> 3) & 63;
            int g = f >> 9;
            int kci = (g % 6) * 32 + (l >> 4) * 8 + j;
            int c   = (g / 6) * 16 + (l & 15);
            int k = kci >> 6, ci = kci & 63;
            w2[f] = f_to_bf16u(W[(k * 64 + c) * 64 + ci]);
        }
    }
}

// ---- kernel 1: persistent pipelined fused conv+agg --------------------------
// grid = 1024 blocks x 256 thr; each block: 16 consecutive chunks (2 t each)
// LDS: xa [50 rows=(t*25+w)][200 kci-pad] bf16 = 20000 B only
__global__ __launch_bounds__(256, 4)
void gcn_main(const float* __restrict__ x, float* __restrict__ ws,
              float* __restrict__ out) {
    __shared__ __align__(16) unsigned short xa16[50 * 200];

    const int tid = threadIdx.x;
    const int l   = tid & 63;
    const int wv  = tid >> 6;
    const int llo = l & 15;
    const int lhi = l >> 4;

    // ---- persistent operand fragments ----
    const unsigned short* a2g = (const unsigned short*)(ws + WS_A2F);
    short8 a2f[5];
    #pragma unroll
    for (int nt = 0; nt < 5; ++nt)
        a2f[nt] = *(const short8*)(a2g + (nt * 64 + l) * 8);

    const unsigned short* w2g = (const unsigned short*)(ws + WS_W2F);
    short8 w2f[6];
    #pragma unroll
    for (int kk = 0; kk < 6; ++kk)
        w2f[kk] = *(const short8*)(w2g + ((wv * 6 + kk) * 64 + l) * 8);

    // bias regs: breg[mt][i] for c = wv*16+lhi*4+i, r = mt*16+llo
    float breg[4][4];
    #pragma unroll
    for (int mt = 0; mt < 4; ++mt) {
        int r = mt * 16 + llo;
        int w2i = (r < 50) ? ((r >= 25) ? r - 25 : r) : 0;
        #pragma unroll
        for (int i = 0; i < 4; ++i)
            breg[mt][i] = ws[WS_BIAS2 + (wv * 16 + lhi * 4 + i) * 25 + w2i];
    }

    float ls[4] = {0.f, 0.f, 0.f, 0.f};
    float lq[4] = {0.f, 0.f, 0.f, 0.f};

    // per-lane G1 source geometry: q in {0,1}, mt = wv*2+q,
    // A-row = mt*16+llo -> t = mt>>2 (llo<16 never carries), ci = row&63, v = lhi*8
    int mtq[2], tq[2], ciq[2];
    #pragma unroll
    for (int q = 0; q < 2; ++q) {
        mtq[q] = wv * 2 + q;
        tq[q]  = mtq[q] >> 2;
        ciq[q] = (mtq[q] * 16 + llo) & 63;
    }

    const size_t cbase_off = (size_t)(wv * 16 + lhi * 4) * 25600 + llo;

    const int chunk0 = blockIdx.x * ITERS;

    f32x4 xr[2][2];
    // ---- prologue: load chunk0's x ----
    {
        int n = chunk0 >> 9, tc = chunk0 & 511;
        #pragma unroll
        for (int q = 0; q < 2; ++q) {
            const float* src = x + (size_t)(n * 64 + ciq[q]) * 25600
                                 + (size_t)(tc * 2 + tq[q]) * 25 + lhi * 8;
            if (lhi < 3) {
                xr[q][0] = *(const f32x4u*)src;
                xr[q][1] = *(const f32x4u*)(src + 4);
            } else {
                f32x4 z = {src[0], 0.f, 0.f, 0.f};
                xr[q][0] = z;
                f32x4 zz = {0.f, 0.f, 0.f, 0.f};
                xr[q][1] = zz;
            }
        }
    }

    #pragma unroll 1
    for (int it = 0; it < ITERS; ++it) {
        const int chunk = chunk0 + it;
        const int n  = chunk >> 9;
        const int tc = chunk & 511;

        // ---- G1: convert + MFMA + xa writes ----
        #pragma unroll
        for (int q = 0; q < 2; ++q) {
            short8 xf = pack8(xr[q][0], xr[q][1]);
            int rb  = mtq[q] * 16 + lhi * 4;
            int t   = rb >> 6;
            int ci4 = rb & 63;
            #pragma unroll
            for (int nt = 0; nt < 5; ++nt) {
                f32x4 z = {0.f, 0.f, 0.f, 0.f};
                f32x4 acc = __builtin_amdgcn_mfma_f32_16x16x32_bf16(xf, a2f[nt], z, 0, 0, 0);
                int col = nt * 16 + llo;
                if (col < 75) {
                    int k = (col >= 50) ? 2 : ((col >= 25) ? 1 : 0);
                    int w = col - k * 25;
                    unsigned int lo = (unsigned int)f_to_bf16u(acc[0]) |
                                      ((unsigned int)f_to_bf16u(acc[1]) << 16);
                    unsigned int hi = (unsigned int)f_to_bf16u(acc[2]) |
                                      ((unsigned int)f_to_bf16u(acc[3]) << 16);
                    uint2 pk; pk.x = lo; pk.y = hi;
                    *(uint2*)(xa16 + (t * 25 + w) * 200 + k * 64 + ci4) = pk;
                }
            }
        }
        __syncthreads();

        // ---- prefetch next chunk's x (xr consumed above) ----
        if (it + 1 < ITERS) {
            int nn = (chunk + 1) >> 9, ntc = (chunk + 1) & 511;
            #pragma unroll
            for (int q = 0; q < 2; ++q) {
                const float* src = x + (size_t)(nn * 64 + ciq[q]) * 25600
                                     + (size_t)(ntc * 2 + tq[q]) * 25 + lhi * 8;
                if (lhi < 3) {
                    xr[q][0] = *(const f32x4u*)src;
                    xr[q][1] = *(const f32x4u*)(src + 4);
                } else {
                    f32x4 z = {src[0], 0.f, 0.f, 0.f};
                    xr[q][0] = z;
                    f32x4 zz = {0.f, 0.f, 0.f, 0.f};
                    xr[q][1] = zz;
                }
            }
        }

        // ---- G2 (operand-swapped: C' rows = channels) + store + stats ----
        const size_t iterbase = (size_t)n * 64 * 25600 + (size_t)tc * 50 + cbase_off;
        #pragma unroll
        for (int mt2 = 0; mt2 < 4; ++mt2) {
            int rr  = mt2 * 16 + llo;
            int row = (rr < 50) ? rr : 0;
            f32x4 acc = {0.f, 0.f, 0.f, 0.f};
            #pragma unroll
            for (int kk = 0; kk < 6; ++kk) {
                short8 bxa = *(const short8*)(xa16 + row * 200 + kk * 32 + lhi * 8);
                acc = __builtin_amdgcn_mfma_f32_16x16x32_bf16(w2f[kk], bxa, acc, 0, 0, 0);
            }
            if (rr < 50) {
                #pragma unroll
                for (int i = 0; i < 4; ++i) {
                    float v = acc[i] + breg[mt2][i];
                    out[iterbase + (size_t)i * 25600 + mt2 * 16] = v;   // + llo in cbase_off
                    ls[i] += v;
                    lq[i] = fmaf(v, v, lq[i]);
                }
            }
        }
        __syncthreads();
    }

    // ---- stats: reduce over llo lanes, atomics once per block ----
    #pragma unroll
    for (int i = 0; i < 4; ++i) {
        #pragma unroll
        for (int m = 1; m <= 8; m <<= 1) {
            ls[i] += __shfl_xor(ls[i], m);
            lq[i] += __shfl_xor(lq[i], m);
        }
    }
    if (llo == 0) {
        int slot = blockIdx.x & 7;
        int cb = wv * 16 + lhi * 4;
        #pragma unroll
        for (int i = 0; i < 4; ++i) {
            atomicAdd(&ws[WS_SUM + slot * 64 + cb + i], ls[i]);
            atomicAdd(&ws[WS_SQ  + slot * 64 + cb + i], lq[i]);
        }
    }
}

// ---- kernel 2: finalize BN stats -------------------------------------------
__global__ void gcn_stats(float* ws, const float* __restrict__ gamma,
                          const float* __restrict__ beta) {
    int c = threadIdx.x;
    if (c < COUT_) {
        float s = 0.f, q = 0.f;
        #pragma unroll
        for (int slot = 0; slot < 8; ++slot) {
            s += ws[WS_SUM + slot * 64 + c];
            q += ws[WS_SQ  + slot * 64 + c];
        }
        const float cnt = (float)(N_ * T_ * V_);   // 819200
        float mu  = s / cnt;
        float var = q / cnt - mu * mu;
        float rs  = rsqrtf(var + EPSV);
        float sc  = gamma[c] * rs;
        ws[WS_SCALE + c] = sc;
        ws[WS_SHIFT + c] = fmaf(-mu, sc, beta[c]);
    }
}

// ---- kernel 3: BN apply + residual + ReLU, in-place on d_out ---------------
__global__ __launch_bounds__(256)
void gcn_finish(const float* __restrict__ x, const float* __restrict__ ws,
                float* __restrict__ out) {
    int bid = blockIdx.x;            // n*64 + c
    int c = bid & 63;
    float sc = ws[WS_SCALE + c];
    float sh = ws[WS_SHIFT + c];
    size_t base4 = (size_t)bid * 6400;
    const float4* x4 = (const float4*)x;
    float4* o4 = (float4*)out;
    #pragma unroll 2
    for (int it = 0; it < 25; ++it) {
        size_t i = base4 + it * 256 + threadIdx.x;
        float4 a  = o4[i];
        float4 xv = x4[i];
        a.x = fmaxf(0.f, fmaf(a.x, sc, sh) + xv.x);
        a.y = fmaxf(0.f, fmaf(a.y, sc, sh) + xv.y);
        a.z = fmaxf(0.f, fmaf(a.z, sc, sh) + xv.z);
        a.w = fmaxf(0.f, fmaf(a.w, sc, sh) + xv.w);
        o4[i] = a;
    }
}

extern "C" void kernel_launch(void* const* d_in, const int* in_sizes, int n_in,
                              void* d_out, int out_size, void* d_ws, size_t ws_size,
                              hipStream_t stream) {
    (void)in_sizes; (void)n_in; (void)out_size; (void)ws_size;
    const float* x     = (const float*)d_in[0];
    const float* W     = (const float*)d_in[1];
    const float* b     = (const float*)d_in[2];
    const float* A     = (const float*)d_in[3];
    const float* PA    = (const float*)d_in[4];
    const float* gamma = (const float*)d_in[5];
    const float* beta  = (const float*)d_in[6];
    float* out = (float*)d_out;
    float* ws  = (float*)d_ws;

    gcn_prep<<<4, 256, 0, stream>>>(A, PA, b, W, ws);
    gcn_main<<<GRID_MAIN, 256, 0, stream>>>(x, ws, out);
    gcn_stats<<<1, 64, 0, stream>>>(ws, gamma, beta);
    gcn_finish<<<N_ * COUT_, 256, 0, stream>>>(x, ws, out);
}